// Round 1
// baseline (317.739 us; speedup 1.0000x reference)
//
#include <hip/hip_runtime.h>
#include <hip/hip_bf16.h>
#include <cfloat>

#define B_ 256
#define N_ 1024
#define D_ 1024
#define E_ 8
#define L_ 1000

// ---------------- Kernel 1: gate scores (memory-bound, reads 1 GiB) -------
// grid 8192 x 256. Each wave: 8 rows of (B*N, D) x gate_w(D,8) -> 64 sums,
// reduced with a distributed butterfly (63 shuffles), 1 store per lane.
__global__ __launch_bounds__(256) void k_gate(const float* __restrict__ feat,
                                              const float* __restrict__ gate_w,
                                              float* __restrict__ scores) {
  __shared__ float gwT[E_ * D_];  // gwT[e][d], 32 KB
  const int t = threadIdx.x;
#pragma unroll
  for (int j = 0; j < 32; ++j) {
    int idx = j * 256 + t;  // flat gate_w index = d*8 + e
    int e = idx & 7, d = idx >> 3;
    gwT[e * D_ + d] = gate_w[idx];
  }
  __syncthreads();

  const int wave = t >> 6, lane = t & 63;
  const long rowBase = ((long)blockIdx.x * 4 + wave) * 8;
  const float* fbase = feat + rowBase * D_;

  float acc[64];  // acc[r*8+e]
#pragma unroll
  for (int j = 0; j < 64; ++j) acc[j] = 0.f;

#pragma unroll
  for (int it = 0; it < 4; ++it) {
    const int d0 = it * 256 + lane * 4;
    float4 f[8];
#pragma unroll
    for (int r = 0; r < 8; ++r) f[r] = *(const float4*)(fbase + r * D_ + d0);
#pragma unroll
    for (int e = 0; e < 8; ++e) {
      const float4 g = *(const float4*)(&gwT[e * D_ + d0]);
#pragma unroll
      for (int r = 0; r < 8; ++r) {
        acc[r * 8 + e] = fmaf(f[r].x, g.x,
                         fmaf(f[r].y, g.y,
                         fmaf(f[r].z, g.z,
                         fmaf(f[r].w, g.w, acc[r * 8 + e]))));
      }
    }
  }

  // Distributed butterfly reduce over 64 lanes x 64 values.
  // After step s, lane keeps (64>>(s+1)) partial sums; lane L ends holding
  // the full sum of value index bitrev6(L).
#pragma unroll
  for (int s = 0; s < 6; ++s) {
    const int m = 1 << s;
    const int half = 32 >> s;
    const bool up = (lane & m) != 0;
#pragma unroll
    for (int j = 0; j < half; ++j) {
      float keep = up ? acc[j + half] : acc[j];
      float send = up ? acc[j] : acc[j + half];
      float recv = __shfl_xor(send, m, 64);
      acc[j] = keep + recv;
    }
  }
  const int idx = ((lane & 1) << 5) | ((lane & 2) << 3) | ((lane & 4) << 1) |
                  ((lane & 8) >> 1) | ((lane & 16) >> 3) | ((lane & 32) >> 5);
  // value idx = r*8+e  ->  scores[(rowBase+r)*8 + e] == scores[rowBase*8 + idx]
  scores[rowBase * 8 + idx] = acc[0];
  // NOTE: gate_b is intentionally unused — softmax over N is invariant to a
  // per-expert additive constant, so it cancels from top_v and comb_w.
}

// ---------------- Kernel 2: per-(b,e) softmax-over-N + top-3 --------------
// grid 512 x 256; one wave per (b,e) pair (2048 pairs).
__global__ __launch_bounds__(256) void k_topk(const float* __restrict__ scores,
                                              int* __restrict__ top_i,
                                              float* __restrict__ comb) {
  const int t = threadIdx.x, wave = t >> 6, lane = t & 63;
  const int pair = blockIdx.x * 4 + wave;
  const int b = pair >> 3, e = pair & 7;
  const float* s = scores + (long)b * N_ * E_ + e;

  float v[16];
#pragma unroll
  for (int j = 0; j < 16; ++j) v[j] = s[(j * 64 + lane) * E_];

  float M[3];
  int I[3];
  float Z = 0.f;
#pragma unroll
  for (int k = 0; k < 3; ++k) {
    float lm = -FLT_MAX;
    int ln = 0x7fffffff;
#pragma unroll
    for (int j = 0; j < 16; ++j) {
      if (v[j] > lm) { lm = v[j]; ln = j * 64 + lane; }
    }
#pragma unroll
    for (int s2 = 1; s2 < 64; s2 <<= 1) {
      float om = __shfl_xor(lm, s2, 64);
      int on = __shfl_xor(ln, s2, 64);
      if (om > lm || (om == lm && on < ln)) { lm = om; ln = on; }
    }
    M[k] = lm;
    I[k] = ln;
    if (k == 0) {  // sum of exp before any masking; M[0] is the global max
      float se = 0.f;
#pragma unroll
      for (int j = 0; j < 16; ++j) se += expf(v[j] - lm);
#pragma unroll
      for (int s2 = 1; s2 < 64; s2 <<= 1) se += __shfl_xor(se, s2, 64);
      Z = se;
    }
    const int slot = ln >> 6, owner = ln & 63;
#pragma unroll
    for (int j = 0; j < 16; ++j)
      if (j == slot && owner == lane) v[j] = -FLT_MAX;  // static indices only
  }

  if (lane == 0) {
    const float p0 = 1.f / Z;                 // exp(M0-M0)/Z
    const float p1 = expf(M[1] - M[0]) / Z;
    const float p2 = expf(M[2] - M[0]) / Z;
    const float c1 = expf(p1 - p0);           // softmax over [p0,p1,p2], max=p0
    const float c2 = expf(p2 - p0);
    const float den = 1.f + c1 + c2;
    top_i[pair * 3 + 0] = I[0];
    top_i[pair * 3 + 1] = I[1];
    top_i[pair * 3 + 2] = I[2];
    comb[pair * 3 + 0] = 1.f / den;
    comb[pair * 3 + 1] = c1 / den;
    comb[pair * 3 + 2] = c2 / den;
  }
}

// ---------------- Kernel 3: weighted gather -> wf[b,e,d] ------------------
// grid 2048 x 256; wf[b*8+e][d] = sum_k comb[k] * feat[b, top_i[k], d]
__global__ __launch_bounds__(256) void k_gather(const float* __restrict__ feat,
                                                const int* __restrict__ top_i,
                                                const float* __restrict__ comb,
                                                float* __restrict__ wf) {
  const int pair = blockIdx.x;
  const int b = pair >> 3;
  const int i0 = top_i[pair * 3 + 0];
  const int i1 = top_i[pair * 3 + 1];
  const int i2 = top_i[pair * 3 + 2];
  const float c0 = comb[pair * 3 + 0];
  const float c1 = comb[pair * 3 + 1];
  const float c2 = comb[pair * 3 + 2];
  const float* f = feat + (long)b * N_ * D_;
  const int d = threadIdx.x * 4;
  const float4 x = *(const float4*)(f + (long)i0 * D_ + d);
  const float4 y = *(const float4*)(f + (long)i1 * D_ + d);
  const float4 z = *(const float4*)(f + (long)i2 * D_ + d);
  float4 o;
  o.x = c0 * x.x + c1 * y.x + c2 * z.x;
  o.y = c0 * x.y + c1 * y.y + c2 * z.y;
  o.z = c0 * x.z + c1 * y.z + c2 * z.z;
  o.w = c0 * x.w + c1 * y.w + c2 * z.w;
  *(float4*)(wf + (long)pair * D_ + d) = o;
}

// ---------------- Kernel 4: classifier partial GEMM (fp32 VALU) -----------
// part[e][b][l] = sum_d wf[b,e,d]*cls_w[e,l,d].  grid 256 x 256:
// block = (mt in 0..1) x (lt in 0..15) x (e in 0..7); 128x64 tile,
// 8x4 register tile per thread, k-transposed LDS tiles (kc=32).
__global__ __launch_bounds__(256) void k_cls(const float* __restrict__ wf,
                                             const float* __restrict__ cls_w,
                                             float* __restrict__ part) {
  __shared__ float A_[32][132];  // [k][m], pad keeps 16B-aligned rows
  __shared__ float Bt[32][68];   // [k][l]
  const int bx = blockIdx.x;
  const int mt = bx & 1, lt = (bx >> 1) & 15, e = bx >> 5;
  const int m0 = mt * 128, l0 = lt * 64;
  const int t = threadIdx.x;
  const int mg = t >> 4, lg = t & 15;  // 8 m's and 4 l's per thread

  float acc[8][4];
#pragma unroll
  for (int r = 0; r < 8; ++r)
#pragma unroll
    for (int c = 0; c < 4; ++c) acc[r][c] = 0.f;

  const int am = t >> 1, ac = t & 1;  // A staging: row am, 16-float half ac
  const int bl = t >> 2, bc = t & 3;  // B staging: row bl, 8-float quarter bc
  const float* agp = wf + ((long)(m0 + am) * 8 + e) * D_ + ac * 16;
  const bool bvalid = (l0 + bl) < L_;
  const float* bgp = cls_w + ((long)e * L_ + (bvalid ? (l0 + bl) : 0)) * D_ + bc * 8;

  for (int d0 = 0; d0 < D_; d0 += 32) {
    __syncthreads();
#pragma unroll
    for (int j = 0; j < 4; ++j) {  // stage A (transpose to [k][m])
      float4 va = *(const float4*)(agp + d0 + j * 4);
      const int k = ac * 16 + j * 4;
      A_[k + 0][am] = va.x;
      A_[k + 1][am] = va.y;
      A_[k + 2][am] = va.z;
      A_[k + 3][am] = va.w;
    }
#pragma unroll
    for (int j = 0; j < 2; ++j) {  // stage B (transpose to [k][l])
      float4 vb;
      if (bvalid) vb = *(const float4*)(bgp + d0 + j * 4);
      else vb = make_float4(0.f, 0.f, 0.f, 0.f);
      const int k = bc * 8 + j * 4;
      Bt[k + 0][bl] = vb.x;
      Bt[k + 1][bl] = vb.y;
      Bt[k + 2][bl] = vb.z;
      Bt[k + 3][bl] = vb.w;
    }
    __syncthreads();
#pragma unroll
    for (int k = 0; k < 32; ++k) {
      const float4 a0 = *(const float4*)&A_[k][mg * 8];
      const float4 a1 = *(const float4*)&A_[k][mg * 8 + 4];
      const float4 b0 = *(const float4*)&Bt[k][lg * 4];
      const float ar[8] = {a0.x, a0.y, a0.z, a0.w, a1.x, a1.y, a1.z, a1.w};
      const float br[4] = {b0.x, b0.y, b0.z, b0.w};
#pragma unroll
      for (int r = 0; r < 8; ++r)
#pragma unroll
        for (int c = 0; c < 4; ++c) acc[r][c] = fmaf(ar[r], br[c], acc[r][c]);
    }
  }

#pragma unroll
  for (int r = 0; r < 8; ++r) {
    const int m = m0 + mg * 8 + r;
#pragma unroll
    for (int c = 0; c < 4; ++c) {
      const int l = l0 + lg * 4 + c;
      if (l < L_) part[(long)e * (B_ * L_) + (long)m * L_ + l] = acc[r][c];
    }
  }
}

// ---------------- Kernel 5: reduce over experts + bias --------------------
__global__ __launch_bounds__(256) void k_reduce(const float* __restrict__ part,
                                                const float* __restrict__ cls_b,
                                                float* __restrict__ out) {
  const int idx = blockIdx.x * 256 + threadIdx.x;
  if (idx >= B_ * L_) return;
  const int l = idx % L_;
  float s = 0.f, bias = 0.f;
#pragma unroll
  for (int e = 0; e < 8; ++e) {
    s += part[(long)e * (B_ * L_) + idx];
    bias += cls_b[e * L_ + l];
  }
  out[idx] = (s + bias) * 0.125f;
}

extern "C" void kernel_launch(void* const* d_in, const int* in_sizes, int n_in,
                              void* d_out, int out_size, void* d_ws, size_t ws_size,
                              hipStream_t stream) {
  const float* feat   = (const float*)d_in[0];
  const float* gate_w = (const float*)d_in[1];
  // d_in[2] = gate_b: mathematically cancels (softmax over N), unused.
  const float* cls_w  = (const float*)d_in[3];
  const float* cls_b  = (const float*)d_in[4];
  float* out = (float*)d_out;

  char* ws = (char*)d_ws;
  // Layout: [0, 8.39MB): scores (k1/k2), reused as part (k4/k5)
  //         [8.39MB, 16.78MB): wf;  then top_i, comb.
  float* scores = (float*)ws;
  float* part   = (float*)ws;  // scores dead after k_topk; safe reuse
  float* wf     = (float*)(ws + 8388608);
  int*   top_i  = (int*)(ws + 16777216);
  float* comb   = (float*)(ws + 16801792);

  k_gate<<<8192, 256, 0, stream>>>(feat, gate_w, scores);
  k_topk<<<512, 256, 0, stream>>>(scores, top_i, comb);
  k_gather<<<2048, 256, 0, stream>>>(feat, top_i, comb, wf);
  k_cls<<<256, 256, 0, stream>>>(wf, cls_w, part);
  k_reduce<<<1000, 256, 0, stream>>>(part, cls_b, out);
}

// Round 2
// 241.446 us; speedup vs baseline: 1.3160x; 1.3160x over previous
//
#include <hip/hip_runtime.h>
#include <hip/hip_bf16.h>
#include <cfloat>

#define B_ 256
#define N_ 1024
#define D_ 1024
#define E_ 8
#define L_ 1000

typedef float f32x4 __attribute__((ext_vector_type(4)));
typedef short bf16x8 __attribute__((ext_vector_type(8)));

__device__ inline unsigned short f2bf(float f) {
  unsigned u = __builtin_bit_cast(unsigned, f);
  u += 0x7fffu + ((u >> 16) & 1u);  // round-to-nearest-even
  return (unsigned short)(u >> 16);
}

// ---------------- Kernel 1: gate scores (memory-bound, reads 1 GiB) -------
// grid 8192 x 256. Each wave: 8 rows of (B*N, D) x gate_w(D,8) -> 64 sums,
// reduced with a distributed butterfly (63 shuffles), 1 store per lane.
__global__ __launch_bounds__(256) void k_gate(const float* __restrict__ feat,
                                              const float* __restrict__ gate_w,
                                              float* __restrict__ scores) {
  __shared__ float gwT[E_ * D_];  // gwT[e][d], 32 KB
  const int t = threadIdx.x;
#pragma unroll
  for (int j = 0; j < 32; ++j) {
    int idx = j * 256 + t;  // flat gate_w index = d*8 + e
    int e = idx & 7, d = idx >> 3;
    gwT[e * D_ + d] = gate_w[idx];
  }
  __syncthreads();

  const int wave = t >> 6, lane = t & 63;
  const long rowBase = ((long)blockIdx.x * 4 + wave) * 8;
  const float* fbase = feat + rowBase * D_;

  float acc[64];  // acc[r*8+e]
#pragma unroll
  for (int j = 0; j < 64; ++j) acc[j] = 0.f;

#pragma unroll
  for (int it = 0; it < 4; ++it) {
    const int d0 = it * 256 + lane * 4;
    float4 f[8];
#pragma unroll
    for (int r = 0; r < 8; ++r) f[r] = *(const float4*)(fbase + r * D_ + d0);
#pragma unroll
    for (int e = 0; e < 8; ++e) {
      const float4 g = *(const float4*)(&gwT[e * D_ + d0]);
#pragma unroll
      for (int r = 0; r < 8; ++r) {
        acc[r * 8 + e] = fmaf(f[r].x, g.x,
                         fmaf(f[r].y, g.y,
                         fmaf(f[r].z, g.z,
                         fmaf(f[r].w, g.w, acc[r * 8 + e]))));
      }
    }
  }

  // Distributed butterfly reduce over 64 lanes x 64 values; lane L ends
  // holding the full sum of value index bitrev6(L).
#pragma unroll
  for (int s = 0; s < 6; ++s) {
    const int m = 1 << s;
    const int half = 32 >> s;
    const bool up = (lane & m) != 0;
#pragma unroll
    for (int j = 0; j < half; ++j) {
      float keep = up ? acc[j + half] : acc[j];
      float send = up ? acc[j] : acc[j + half];
      float recv = __shfl_xor(send, m, 64);
      acc[j] = keep + recv;
    }
  }
  const int idx = ((lane & 1) << 5) | ((lane & 2) << 3) | ((lane & 4) << 1) |
                  ((lane & 8) >> 1) | ((lane & 16) >> 3) | ((lane & 32) >> 5);
  scores[rowBase * 8 + idx] = acc[0];
  // gate_b intentionally unused: softmax over N is invariant to a per-expert
  // additive constant, so it cancels from top_v and comb_w.
}

// ---------------- Kernel 2: per-(b,e) softmax-over-N + top-3 --------------
__global__ __launch_bounds__(256) void k_topk(const float* __restrict__ scores,
                                              int* __restrict__ top_i,
                                              float* __restrict__ comb) {
  const int t = threadIdx.x, wave = t >> 6, lane = t & 63;
  const int pair = blockIdx.x * 4 + wave;
  const int b = pair >> 3, e = pair & 7;
  const float* s = scores + (long)b * N_ * E_ + e;

  float v[16];
#pragma unroll
  for (int j = 0; j < 16; ++j) v[j] = s[(j * 64 + lane) * E_];

  float M[3];
  int I[3];
  float Z = 0.f;
#pragma unroll
  for (int k = 0; k < 3; ++k) {
    float lm = -FLT_MAX;
    int ln = 0x7fffffff;
#pragma unroll
    for (int j = 0; j < 16; ++j) {
      if (v[j] > lm) { lm = v[j]; ln = j * 64 + lane; }
    }
#pragma unroll
    for (int s2 = 1; s2 < 64; s2 <<= 1) {
      float om = __shfl_xor(lm, s2, 64);
      int on = __shfl_xor(ln, s2, 64);
      if (om > lm || (om == lm && on < ln)) { lm = om; ln = on; }
    }
    M[k] = lm;
    I[k] = ln;
    if (k == 0) {
      float se = 0.f;
#pragma unroll
      for (int j = 0; j < 16; ++j) se += expf(v[j] - lm);
#pragma unroll
      for (int s2 = 1; s2 < 64; s2 <<= 1) se += __shfl_xor(se, s2, 64);
      Z = se;
    }
    const int slot = ln >> 6, owner = ln & 63;
#pragma unroll
    for (int j = 0; j < 16; ++j)
      if (j == slot && owner == lane) v[j] = -FLT_MAX;
  }

  if (lane == 0) {
    const float p0 = 1.f / Z;
    const float p1 = expf(M[1] - M[0]) / Z;
    const float p2 = expf(M[2] - M[0]) / Z;
    const float c1 = expf(p1 - p0);
    const float c2 = expf(p2 - p0);
    const float den = 1.f + c1 + c2;
    top_i[pair * 3 + 0] = I[0];
    top_i[pair * 3 + 1] = I[1];
    top_i[pair * 3 + 2] = I[2];
    comb[pair * 3 + 0] = 1.f / den;
    comb[pair * 3 + 1] = c1 / den;
    comb[pair * 3 + 2] = c2 / den;
  }
}

// ---------------- Kernel 3: weighted gather -> wf[b,e,d] in BF16 ----------
__global__ __launch_bounds__(256) void k_gather(const float* __restrict__ feat,
                                                const int* __restrict__ top_i,
                                                const float* __restrict__ comb,
                                                unsigned short* __restrict__ wf) {
  const int pair = blockIdx.x;
  const int b = pair >> 3;
  const int i0 = top_i[pair * 3 + 0];
  const int i1 = top_i[pair * 3 + 1];
  const int i2 = top_i[pair * 3 + 2];
  const float c0 = comb[pair * 3 + 0];
  const float c1 = comb[pair * 3 + 1];
  const float c2 = comb[pair * 3 + 2];
  const float* f = feat + (long)b * N_ * D_;
  const int d = threadIdx.x * 4;
  const float4 x = *(const float4*)(f + (long)i0 * D_ + d);
  const float4 y = *(const float4*)(f + (long)i1 * D_ + d);
  const float4 z = *(const float4*)(f + (long)i2 * D_ + d);
  ushort4 o;
  o.x = f2bf(c0 * x.x + c1 * y.x + c2 * z.x);
  o.y = f2bf(c0 * x.y + c1 * y.y + c2 * z.y);
  o.z = f2bf(c0 * x.z + c1 * y.z + c2 * z.z);
  o.w = f2bf(c0 * x.w + c1 * y.w + c2 * z.w);
  *(ushort4*)(wf + (long)pair * D_ + d) = o;
}

// ---------------- Kernel 4: classifier GEMM via bf16 MFMA -----------------
// part[e][b][l] = sum_d wf[b,e,d]*cls_w[e,l,d].
// Tiles: BM=128 (b) x BN=64 (l) x BK=64, grid = 8e * 2bt * 16lt = 256 blocks.
// 4 waves in 2x2; each wave 64x32 = 4x2 fragments of 16x16x32 bf16 MFMA.
// A (wf) is bf16 in global; B (cls_w) converted fp32->bf16 during staging.
// LDS tiles stored as 16B granules, XOR-swizzled: granule g at (g ^ (row&7)).
__global__ __launch_bounds__(256) void k_cls(const unsigned short* __restrict__ wf,
                                             const float* __restrict__ cls_w,
                                             float* __restrict__ part) {
  __shared__ uint4 Ag[2][128 * 8];  // 2 x 16 KB: [row(b)][8 granules of 8 bf16]
  __shared__ uint4 Bg[2][64 * 8];   // 2 x  8 KB: [row(l)][8 granules]

  const int bx = blockIdx.x;
  const int e = bx >> 5, bt = (bx >> 4) & 1, lt = bx & 15;
  const int m0 = bt * 128, l0 = lt * 64;
  const int t = threadIdx.x;
  const int w = t >> 6, lane = t & 63;
  const int wm = w >> 1, wn = w & 1;

  // staging maps
  const int arow = t >> 1, ah = t & 1;                 // A: 128 rows x 2 halves
  const int brow = t >> 2, bq = t & 3;                 // B: 64 rows x 4 quarters
  const int lg = (l0 + brow < L_) ? (l0 + brow) : (L_ - 1);  // clamp OOB rows
  const unsigned short* agp = wf + ((size_t)(m0 + arow) * E_ + e) * D_ + ah * 32;
  const float* bgp = cls_w + ((size_t)e * L_ + lg) * D_ + bq * 16;

  uint4 areg[4];
  float4 breg[4];

  auto load_regs = [&](int step) {
    const int d0 = step * 64;
#pragma unroll
    for (int j = 0; j < 4; ++j)
      areg[j] = *(const uint4*)(agp + d0 + j * 8);
#pragma unroll
    for (int j = 0; j < 4; ++j)
      breg[j] = *(const float4*)(bgp + d0 + j * 4);
  };

  auto write_lds = [&](int c) {
#pragma unroll
    for (int j = 0; j < 4; ++j)
      Ag[c][arow * 8 + ((ah * 4 + j) ^ (arow & 7))] = areg[j];
#pragma unroll
    for (int j = 0; j < 2; ++j) {
      const float4 x = breg[j * 2], y = breg[j * 2 + 1];
      uint4 p;
      p.x = (unsigned)f2bf(x.x) | ((unsigned)f2bf(x.y) << 16);
      p.y = (unsigned)f2bf(x.z) | ((unsigned)f2bf(x.w) << 16);
      p.z = (unsigned)f2bf(y.x) | ((unsigned)f2bf(y.y) << 16);
      p.w = (unsigned)f2bf(y.z) | ((unsigned)f2bf(y.w) << 16);
      Bg[c][brow * 8 + ((bq * 2 + j) ^ (brow & 7))] = p;
    }
  };

  f32x4 acc[4][2];
#pragma unroll
  for (int m = 0; m < 4; ++m)
#pragma unroll
    for (int n = 0; n < 2; ++n) acc[m][n] = (f32x4){0.f, 0.f, 0.f, 0.f};

  const int l15 = lane & 15, lhi = lane >> 4, l7 = lane & 7;

  load_regs(0);
  for (int step = 0; step < 16; ++step) {
    const int c = step & 1;
    write_lds(c);
    if (step < 15) load_regs(step + 1);
    __syncthreads();
#pragma unroll
    for (int ks = 0; ks < 2; ++ks) {
      bf16x8 a[4], b[2];
#pragma unroll
      for (int m = 0; m < 4; ++m) {
        const int row = wm * 64 + m * 16 + l15;
        a[m] = __builtin_bit_cast(bf16x8,
                 Ag[c][row * 8 + ((ks * 4 + lhi) ^ l7)]);
      }
#pragma unroll
      for (int n = 0; n < 2; ++n) {
        const int row = wn * 32 + n * 16 + l15;
        b[n] = __builtin_bit_cast(bf16x8,
                 Bg[c][row * 8 + ((ks * 4 + lhi) ^ l7)]);
      }
#pragma unroll
      for (int m = 0; m < 4; ++m)
#pragma unroll
        for (int n = 0; n < 2; ++n)
          acc[m][n] = __builtin_amdgcn_mfma_f32_16x16x32_bf16(
              a[m], b[n], acc[m][n], 0, 0, 0);
    }
    __syncthreads();
  }

  // C/D layout: col = lane&15, row = (lane>>4)*4 + j   [m89-verified]
#pragma unroll
  for (int m = 0; m < 4; ++m) {
#pragma unroll
    for (int n = 0; n < 2; ++n) {
      const int col = l0 + wn * 32 + n * 16 + l15;
      if (col < L_) {
#pragma unroll
        for (int j = 0; j < 4; ++j) {
          const int row = m0 + wm * 64 + m * 16 + lhi * 4 + j;
          part[((size_t)e * B_ + row) * L_ + col] = acc[m][n][j];
        }
      }
    }
  }
}

// ---------------- Kernel 5: reduce over experts + bias --------------------
__global__ __launch_bounds__(256) void k_reduce(const float* __restrict__ part,
                                                const float* __restrict__ cls_b,
                                                float* __restrict__ out) {
  const int idx = blockIdx.x * 256 + threadIdx.x;
  if (idx >= B_ * L_) return;
  const int l = idx % L_;
  float s = 0.f, bias = 0.f;
#pragma unroll
  for (int e = 0; e < 8; ++e) {
    s += part[(long)e * (B_ * L_) + idx];
    bias += cls_b[e * L_ + l];
  }
  out[idx] = (s + bias) * 0.125f;
}

extern "C" void kernel_launch(void* const* d_in, const int* in_sizes, int n_in,
                              void* d_out, int out_size, void* d_ws, size_t ws_size,
                              hipStream_t stream) {
  const float* feat   = (const float*)d_in[0];
  const float* gate_w = (const float*)d_in[1];
  // d_in[2] = gate_b: mathematically cancels (softmax over N), unused.
  const float* cls_w  = (const float*)d_in[3];
  const float* cls_b  = (const float*)d_in[4];
  float* out = (float*)d_out;

  char* ws = (char*)d_ws;
  // Layout: [0, 8.39MB): scores (k1/k2), reused as part (k4/k5)
  //         [8.39MB, +4.2MB): wf (bf16);  then top_i, comb.
  float*          scores = (float*)ws;
  float*          part   = (float*)ws;  // scores dead after k_topk
  unsigned short* wfb    = (unsigned short*)(ws + 8388608);
  int*            top_i  = (int*)(ws + 16777216);
  float*          comb   = (float*)(ws + 16801792);

  k_gate<<<8192, 256, 0, stream>>>(feat, gate_w, scores);
  k_topk<<<512, 256, 0, stream>>>(scores, top_i, comb);
  k_gather<<<2048, 256, 0, stream>>>(feat, top_i, comb, wfb);
  k_cls<<<256, 256, 0, stream>>>(wfb, cls_w, part);
  k_reduce<<<1000, 256, 0, stream>>>(part, cls_b, out);
}